// Round 3
// baseline (628.639 us; speedup 1.0000x reference)
//
#include <hip/hip_runtime.h>

#define N_ROWS 100000
#define M_NBR  12
#define C_DIM  64
#define F_DIM  41
#define E_TOT  (N_ROWS * M_NBR)

// ---------------------------------------------------------------------------
// Kernel A: s_e = (softplus(x_e @ W1 + b1) . w2[:,0] + b2[0]) * c
// 4 edges/thread (block = 1 wave of 64, tile = 256 edges). W1 rows via
// wave-uniform s_load; the per-row scalar-load latency is amortized over
// 164 fmac (4 edges x 41 outputs). K is split 21+20 so the fp32 x-tile is
// 21.5 KB -> 7 single-wave blocks/CU for latency hiding.
// ---------------------------------------------------------------------------
#define A_TILE 256
#define KH0    21
#define KH1    20

__global__ __launch_bounds__(64) void edge_mlp_kernel(
    const float* __restrict__ nbr_fea,   // [E, F]
    const float* __restrict__ w1,        // [F, F]
    const float* __restrict__ b1,        // [F]
    const float* __restrict__ w2,        // [F, 9]
    const float* __restrict__ b2,        // [9]
    float* __restrict__ s_out)           // [E]
{
    __shared__ float lx[A_TILE * KH0];   // 21504 B, row stride 21 (odd -> conflict-free)

    const int t    = threadIdx.x;
    const long base = (long)blockIdx.x * A_TILE;
    int rem = (int)((long)E_TOT - base);
    const int ntile = rem < A_TILE ? rem : A_TILE;

    if (ntile < A_TILE) {                // zero-fill so garbage never becomes NaN
        for (int i = t; i < A_TILE * KH0; i += 64) lx[i] = 0.0f;
        __syncthreads();
    }

    float h[4][F_DIM];
    #pragma unroll
    for (int j = 0; j < F_DIM; ++j) {
        float bj = b1[j];                                   // s_load
        h[0][j] = bj; h[1][j] = bj; h[2][j] = bj; h[3][j] = bj;
    }

    // ---- stage + compute, K half 0 (k = 0..20) ----
    {
        const int nel = ntile * KH0;
        for (int i = t; i < nel; i += 64) {
            int e = i / KH0, k = i - e * KH0;
            lx[i] = nbr_fea[(long)(base + e) * F_DIM + k];  // coalesced-ish (L2 fixes)
        }
    }
    __syncthreads();
    #pragma unroll 2
    for (int k = 0; k < KH0; ++k) {
        const float* wrow = w1 + k * F_DIM;                 // uniform -> s_load
        float x0 = lx[(t      ) * KH0 + k];
        float x1 = lx[(t +  64) * KH0 + k];
        float x2 = lx[(t + 128) * KH0 + k];
        float x3 = lx[(t + 192) * KH0 + k];
        #pragma unroll
        for (int j = 0; j < F_DIM; ++j) {
            float w = wrow[j];
            h[0][j] = fmaf(x0, w, h[0][j]);
            h[1][j] = fmaf(x1, w, h[1][j]);
            h[2][j] = fmaf(x2, w, h[2][j]);
            h[3][j] = fmaf(x3, w, h[3][j]);
        }
    }
    __syncthreads();

    // ---- stage + compute, K half 1 (k = 21..40), same LDS buffer, stride 21 ----
    {
        const int nel = ntile * KH1;
        for (int i = t; i < nel; i += 64) {
            int e = i / KH1, k = i - e * KH1;
            lx[e * KH0 + k] = nbr_fea[(long)(base + e) * F_DIM + KH0 + k];
        }
    }
    __syncthreads();
    #pragma unroll 2
    for (int k = 0; k < KH1; ++k) {
        const float* wrow = w1 + (KH0 + k) * F_DIM;
        float x0 = lx[(t      ) * KH0 + k];
        float x1 = lx[(t +  64) * KH0 + k];
        float x2 = lx[(t + 128) * KH0 + k];
        float x3 = lx[(t + 192) * KH0 + k];
        #pragma unroll
        for (int j = 0; j < F_DIM; ++j) {
            float w = wrow[j];
            h[0][j] = fmaf(x0, w, h[0][j]);
            h[1][j] = fmaf(x1, w, h[1][j]);
            h[2][j] = fmaf(x2, w, h[2][j]);
            h[3][j] = fmaf(x3, w, h[3][j]);
        }
    }

    // ---- epilogue: softplus + dot with w2[:,0] ----
    #pragma unroll
    for (int i = 0; i < 4; ++i) {
        long e = base + t + 64 * i;
        if (e < (long)E_TOT) {
            float acc = b2[0];
            #pragma unroll
            for (int j = 0; j < F_DIM; ++j) {
                float v = h[i][j];
                float sp = fmaxf(v, 0.0f) + __logf(1.0f + __expf(-fabsf(v)));
                acc = fmaf(sp, w2[j * 9], acc);             // w2 col 0, s_load
            }
            s_out[e] = acc * (0.28209479177387814f / 12.0f);
        }
    }
}

// ---------------------------------------------------------------------------
// Kernel B (fused): acc_r = sum_j s_rj * atom_fea[idx_rj][:]  (lane = channel,
// coalesced 256B row gathers), then out_r = acc_r @ (tp_w/8) via v_readlane
// outer-product -- uses the per-SIMD VALU pipe instead of the CU-shared LDS
// broadcast pipe, and avoids materializing/re-reading afT (51 MB HBM saved).
// ---------------------------------------------------------------------------
__global__ __launch_bounds__(256) void gather_transform_kernel(
    const float* __restrict__ atom_fea,  // [N, C]
    const int*   __restrict__ nbr_idx,   // [N, M]
    const float* __restrict__ s,         // [E]
    const float* __restrict__ tp_w,      // [C, C]
    float* __restrict__ out)             // [N, C]
{
    __shared__ int   lidx[64 * M_NBR];
    __shared__ float lsv [64 * M_NBR];

    const int tid  = threadIdx.x;
    const int lane = tid & 63;
    const int wv   = tid >> 6;
    const int row0 = blockIdx.x * 64;

    // stage this block's idx & s (coalesced)
    const long ebase = (long)row0 * M_NBR;
    for (int i = tid; i < 64 * M_NBR; i += 256) {
        long g = ebase + i;
        bool ok = g < (long)E_TOT;
        lidx[i] = ok ? nbr_idx[g] : 0;
        lsv[i]  = ok ? s[g]       : 0.0f;
    }

    // per-lane column of tp_w, pre-scaled by 1/sqrt(C)=1/8 (coalesced loads)
    float Tc[64];
    #pragma unroll
    for (int k = 0; k < 64; ++k) Tc[k] = tp_w[k * 64 + lane] * 0.125f;
    __syncthreads();

    float acc[16];
    #pragma unroll
    for (int i = 0; i < 16; ++i) acc[i] = 0.0f;

    #pragma unroll 4
    for (int i = 0; i < 16; ++i) {
        const int rl = wv * 16 + i;
        #pragma unroll
        for (int j = 0; j < M_NBR; ++j) {
            int   idx = lidx[rl * M_NBR + j];   // LDS broadcast
            float sv  = lsv [rl * M_NBR + j];
            acc[i] = fmaf(sv, atom_fea[(long)idx * C_DIM + lane], acc[i]);
        }
    }

    // transform epilogue: out[r][lane] = sum_k acc_r[k] * T[k][lane]
    #pragma unroll
    for (int i = 0; i < 16; ++i) {
        int r = row0 + wv * 16 + i;
        if (r < N_ROWS) {                       // wave-uniform guard
            float o = 0.0f;
            #pragma unroll
            for (int k = 0; k < 64; ++k) {
                float a = __int_as_float(__builtin_amdgcn_readlane(__float_as_int(acc[i]), k));
                o = fmaf(a, Tc[k], o);
            }
            out[(long)r * C_DIM + lane] = o;    // coalesced
        }
    }
}

extern "C" void kernel_launch(void* const* d_in, const int* in_sizes, int n_in,
                              void* d_out, int out_size, void* d_ws, size_t ws_size,
                              hipStream_t stream) {
    const float* atom_fea = (const float*)d_in[0];
    const float* nbr_fea  = (const float*)d_in[1];
    const int*   nbr_idx  = (const int*)  d_in[2];
    // d_in[3] = pos : dead (only the constant l=0 SH channel couples)
    const float* w1   = (const float*)d_in[4];
    const float* b1   = (const float*)d_in[5];
    const float* w2   = (const float*)d_in[6];
    const float* b2   = (const float*)d_in[7];
    const float* tp_w = (const float*)d_in[8];

    float* s   = (float*)d_ws;                   // 4.8 MB scratch
    float* out = (float*)d_out;

    const int blocksA = (E_TOT + A_TILE - 1) / A_TILE;       // 4688
    edge_mlp_kernel<<<blocksA, 64, 0, stream>>>(nbr_fea, w1, b1, w2, b2, s);

    const int blocksB = (N_ROWS + 63) / 64;                  // 1563
    gather_transform_kernel<<<blocksB, 256, 0, stream>>>(atom_fea, nbr_idx, s, tp_w, out);
}

// Round 4
// 571.289 us; speedup vs baseline: 1.1004x; 1.1004x over previous
//
#include <hip/hip_runtime.h>

#define N_ROWS 100000
#define M_NBR  12
#define C_DIM  64
#define F_DIM  41
#define E_TOT  (N_ROWS * M_NBR)

// ---------------------------------------------------------------------------
// Kernel A: s_e = (softplus(x_e @ W1 + b1) . w2[:,0] + b2[0]) * c
// R2 body (1 edge/thread, VGPR ~68, s_load weights) + K-split staging so the
// LDS tile is 21.5 KB -> 7 blocks/CU x 4 waves = 28 waves/CU (87% occupancy)
// instead of R2's 42 KB -> 12 waves (31%). Both phases use row stride 21
// (odd -> conflict-free); phase 1 wastes 1 float/row rather than using
// stride 20 (8-way conflict).
// ---------------------------------------------------------------------------
#define KH0 21
#define KH1 20

__global__ __launch_bounds__(256, 7) void edge_mlp_kernel(
    const float* __restrict__ nbr_fea,   // [E, F]
    const float* __restrict__ w1,        // [F, F]
    const float* __restrict__ b1,        // [F]
    const float* __restrict__ w2,        // [F, 9]
    const float* __restrict__ b2,        // [9]
    float* __restrict__ s_out)           // [E]
{
    __shared__ float lx[256 * KH0];      // 21504 B

    const int t = threadIdx.x;
    const long base = (long)blockIdx.x * 256;
    int rem = (int)((long)E_TOT - base);
    const int ntile = rem < 256 ? rem : 256;
    const bool act = t < ntile;

    float h[F_DIM];
    #pragma unroll
    for (int j = 0; j < F_DIM; ++j) h[j] = b1[j];           // s_load

    // ---- phase 0: stage k = 0..20 (coalesced-ish runs of 84 B) ----
    {
        const int nel = ntile * KH0;
        for (int i = t; i < nel; i += 256) {
            int e = i / KH0, k = i - e * KH0;
            lx[i] = nbr_fea[(base + e) * F_DIM + k];
        }
    }
    __syncthreads();
    if (act) {
        const float* xr = lx + t * KH0;
        #pragma unroll 3
        for (int k = 0; k < KH0; ++k) {
            float xk = xr[k];                                // ds_read_b32, stride 21
            const float* wrow = w1 + k * F_DIM;              // uniform -> s_load
            #pragma unroll
            for (int j = 0; j < F_DIM; ++j) h[j] = fmaf(xk, wrow[j], h[j]);
        }
    }
    __syncthreads();

    // ---- phase 1: stage k = 21..40, same buffer, keep stride 21 ----
    {
        const int nel = ntile * KH1;
        for (int i = t; i < nel; i += 256) {
            int e = i / KH1, k = i - e * KH1;
            lx[e * KH0 + k] = nbr_fea[(base + e) * F_DIM + KH0 + k];
        }
    }
    __syncthreads();
    if (act) {
        const float* xr = lx + t * KH0;
        #pragma unroll 3
        for (int k = 0; k < KH1; ++k) {
            float xk = xr[k];
            const float* wrow = w1 + (KH0 + k) * F_DIM;
            #pragma unroll
            for (int j = 0; j < F_DIM; ++j) h[j] = fmaf(xk, wrow[j], h[j]);
        }

        // ---- epilogue: softplus + dot with w2[:,0] ----
        float acc = b2[0];
        #pragma unroll
        for (int j = 0; j < F_DIM; ++j) {
            float v = h[j];
            float sp = fmaxf(v, 0.0f) + __logf(1.0f + __expf(-fabsf(v)));
            acc = fmaf(sp, w2[j * 9], acc);                  // w2 col 0, s_load
        }
        s_out[base + t] = acc * (0.28209479177387814f / 12.0f);
    }
}

// ---------------------------------------------------------------------------
// Kernel B (fused): acc_r = sum_j s_rj * atom_fea[idx_rj][:] (lane = channel,
// coalesced 256B row gathers), then out_r = acc_r @ (tp_w/8) via v_readlane
// outer-product on the VALU pipe (no LDS broadcast, no afT round-trip).
// Unchanged from R3 (passed, absmax 4.9e-4).
// ---------------------------------------------------------------------------
__global__ __launch_bounds__(256) void gather_transform_kernel(
    const float* __restrict__ atom_fea,  // [N, C]
    const int*   __restrict__ nbr_idx,   // [N, M]
    const float* __restrict__ s,         // [E]
    const float* __restrict__ tp_w,      // [C, C]
    float* __restrict__ out)             // [N, C]
{
    __shared__ int   lidx[64 * M_NBR];
    __shared__ float lsv [64 * M_NBR];

    const int tid  = threadIdx.x;
    const int lane = tid & 63;
    const int wv   = tid >> 6;
    const int row0 = blockIdx.x * 64;

    const long ebase = (long)row0 * M_NBR;
    for (int i = tid; i < 64 * M_NBR; i += 256) {
        long g = ebase + i;
        bool ok = g < (long)E_TOT;
        lidx[i] = ok ? nbr_idx[g] : 0;
        lsv[i]  = ok ? s[g]       : 0.0f;
    }

    float Tc[64];
    #pragma unroll
    for (int k = 0; k < 64; ++k) Tc[k] = tp_w[k * 64 + lane] * 0.125f;
    __syncthreads();

    float acc[16];
    #pragma unroll
    for (int i = 0; i < 16; ++i) acc[i] = 0.0f;

    #pragma unroll 4
    for (int i = 0; i < 16; ++i) {
        const int rl = wv * 16 + i;
        #pragma unroll
        for (int j = 0; j < M_NBR; ++j) {
            int   idx = lidx[rl * M_NBR + j];   // LDS broadcast
            float sv  = lsv [rl * M_NBR + j];
            acc[i] = fmaf(sv, atom_fea[(long)idx * C_DIM + lane], acc[i]);
        }
    }

    #pragma unroll
    for (int i = 0; i < 16; ++i) {
        int r = row0 + wv * 16 + i;
        if (r < N_ROWS) {                       // wave-uniform guard
            float o = 0.0f;
            #pragma unroll
            for (int k = 0; k < 64; ++k) {
                float a = __int_as_float(__builtin_amdgcn_readlane(__float_as_int(acc[i]), k));
                o = fmaf(a, Tc[k], o);
            }
            out[(long)r * C_DIM + lane] = o;    // coalesced
        }
    }
}

extern "C" void kernel_launch(void* const* d_in, const int* in_sizes, int n_in,
                              void* d_out, int out_size, void* d_ws, size_t ws_size,
                              hipStream_t stream) {
    const float* atom_fea = (const float*)d_in[0];
    const float* nbr_fea  = (const float*)d_in[1];
    const int*   nbr_idx  = (const int*)  d_in[2];
    // d_in[3] = pos : dead (only the constant l=0 SH channel couples)
    const float* w1   = (const float*)d_in[4];
    const float* b1   = (const float*)d_in[5];
    const float* w2   = (const float*)d_in[6];
    const float* b2   = (const float*)d_in[7];
    const float* tp_w = (const float*)d_in[8];

    float* s   = (float*)d_ws;                   // 4.8 MB scratch
    float* out = (float*)d_out;

    const int blocksA = (E_TOT + 255) / 256;     // 4688
    edge_mlp_kernel<<<blocksA, 256, 0, stream>>>(nbr_fea, w1, b1, w2, b2, s);

    const int blocksB = (N_ROWS + 63) / 64;      // 1563
    gather_transform_kernel<<<blocksB, 256, 0, stream>>>(atom_fea, nbr_idx, s, tp_w, out);
}